// Round 10
// baseline (1471.824 us; speedup 1.0000x reference)
//
#include <hip/hip_runtime.h>

#define B_SZ   32
#define S_LEN  512
#define HID    768
#define DH     384
#define G4     1536
#define NPOS   16384   // B_SZ * S_LEN
#define EPS_C  0.5f
#define NCH    24576   // B_SZ * HID channels
#define CHK    64      // gate-scan chunk length
#define NCHK   8       // S_LEN / CHK

typedef _Float16 h2 __attribute__((ext_vector_type(2)));
typedef short bf16x8 __attribute__((ext_vector_type(8)));
typedef float f32x4 __attribute__((ext_vector_type(4)));

static __device__ __forceinline__ float sigm(float x) { return 1.0f / (1.0f + __expf(-x)); }
static __device__ __forceinline__ float tanh_fast(float x) {
    return 1.0f - 2.0f / (__expf(2.0f * x) + 1.0f);
}

static __device__ __forceinline__ unsigned short f2bf(float f) {
    union { float f; unsigned u; } v; v.f = f;
    unsigned r = v.u + 0x7FFF + ((v.u >> 16) & 1);
    return (unsigned short)(r >> 16);
}
static __device__ __forceinline__ float bf2f(unsigned short u) {
    union { unsigned u; float f; } v; v.u = ((unsigned)u) << 16; return v.f;
}

static __device__ __forceinline__ float wred(float v) {
#pragma unroll
    for (int off = 32; off > 0; off >>= 1) v += __shfl_down(v, off, 64);
    return v;
}

static __device__ __forceinline__ float dot2acc(h2 a, h2 b, float c) {
#if __has_builtin(__builtin_amdgcn_fdot2)
    return __builtin_amdgcn_fdot2(a, b, c, false);
#else
    return c + (float)a.x * (float)b.x + (float)a.y * (float)b.y;
#endif
}

// ---------------------------------------------------------------------------
// K0a: pack w_hh fp32 [1536,384] -> fp16-pair u32 [2][1536][192]  (scan wts)
// ---------------------------------------------------------------------------
__global__ void wprep(const float* __restrict__ wf, const float* __restrict__ wb,
                      unsigned* __restrict__ wpk) {
    int gid = blockIdx.x * 256 + threadIdx.x;       // < 589824
    int d = (gid >= 294912) ? 1 : 0;
    int j = gid - d * 294912;
    const float* src = d ? wb : wf;
    _Float16 a = (_Float16)src[2 * j];
    _Float16 b = (_Float16)src[2 * j + 1];
    unsigned pa = __builtin_bit_cast(unsigned short, a);
    unsigned pb = __builtin_bit_cast(unsigned short, b);
    wpk[(size_t)d * 294912 + j] = pa | (pb << 16);
}

// ---------------------------------------------------------------------------
// K0b: fp32 -> bf16 cast (n multiple of 4)
// ---------------------------------------------------------------------------
__global__ __launch_bounds__(256) void cast_bf16(
    const float* __restrict__ src, unsigned short* __restrict__ dst, int n4) {
    int i = blockIdx.x * 256 + threadIdx.x;
    if (i >= n4) return;
    float4 v = *(const float4*)(src + (size_t)i * 4);
    ushort4 o;
    o.x = f2bf(v.x); o.y = f2bf(v.y); o.z = f2bf(v.z); o.w = f2bf(v.w);
    *(ushort4*)(dst + (size_t)i * 4) = o;
}

// ---------------------------------------------------------------------------
// K0c: W_gate [K=768][N=768] -> bf16 transposed [N][K] (read-coalesced)
// ---------------------------------------------------------------------------
__global__ __launch_bounds__(256) void wgt_prep(
    const float* __restrict__ Wg, unsigned short* __restrict__ Wgt) {
    int i = blockIdx.x * 256 + threadIdx.x;          // < 589824
    int k = i / 768, n = i - k * 768;
    Wgt[(size_t)n * 768 + k] = f2bf(Wg[i]);
}

// ---------------------------------------------------------------------------
// K1: z_t head. One wave / position. NO atomics: per-block partial sums.
// ---------------------------------------------------------------------------
__global__ __launch_bounds__(256) void zt_kernel(
    const float* __restrict__ x, const int* __restrict__ amask,
    const int* __restrict__ labn, const float* __restrict__ Wfc,
    const float* __restrict__ bfc, const float* __restrict__ Wtr,
    float* __restrict__ alpha, float* __restrict__ zsp,
    float* __restrict__ p0, float* __restrict__ p2) {
    const int gid  = blockIdx.x * blockDim.x + threadIdx.x;
    const int pos  = gid >> 6, lane = gid & 63, wv = threadIdx.x >> 6;
    __shared__ float r0[4], r2[4];
    const float* xp = x + (size_t)pos * HID;
    float a0 = 0.f, a1 = 0.f, a2 = 0.f;
#pragma unroll
    for (int j = 0; j < 12; ++j) {
        int k = lane + (j << 6);
        float xv = xp[k];
        a0 += xv * Wfc[k * 3 + 0];
        a1 += xv * Wfc[k * 3 + 1];
        a2 += xv * Wfc[k * 3 + 2];
    }
    a0 = wred(a0); a1 = wred(a1); a2 = wred(a2);
    if (lane == 0) {
        float z0 = a0 + bfc[0], z1 = a1 + bfc[1], z2 = a2 + bfc[2];
        float mx = fmaxf(z0, fmaxf(z1, z2));
        float e0 = __expf(z0 - mx), e1 = __expf(z1 - mx), e2 = __expf(z2 - mx);
        float se = e0 + e1 + e2;
        float m  = (float)amask[pos];
        int  lab = labn[pos];
        float zl = (lab == 0) ? z0 : ((lab == 1) ? z1 : z2);
        r0[wv] = (mx + __logf(se) - zl) * m;
        r2[wv] = m;
        float q0 = e0 / se, q1 = e1 / se, q2 = e2 / se;
        alpha[pos] = EPS_C * (q0 * q0 + q1 * q1 + q2 * q2);
#pragma unroll
        for (int cc = 0; cc < 7; ++cc)
            zsp[(size_t)pos * 7 + cc] = z0 * Wtr[cc] + z1 * Wtr[7 + cc] + z2 * Wtr[14 + cc];
    }
    __syncthreads();
    if (threadIdx.x == 0) {
        p0[blockIdx.x] = r0[0] + r0[1] + r0[2] + r0[3];
        p2[blockIdx.x] = r2[0] + r2[1] + r2[2] + r2[3];
    }
}

// ---------------------------------------------------------------------------
// K2: bf16 MFMA GEMM.  C[M,N] = A[M,K] * B[N,K]^T.
//     mode 0: +bias, bf16 out.   mode 1: sigmoid, fp32 out (no bias).
// ---------------------------------------------------------------------------
__global__ __launch_bounds__(256) void gemm_mfma(
    const unsigned short* __restrict__ A, const unsigned short* __restrict__ B,
    const float* __restrict__ bias, void* __restrict__ Cout,
    int M, int N, int K, int mode) {
    __shared__ __align__(16) unsigned short As[128][40];   // +8 pad: conflict-free
    __shared__ __align__(16) unsigned short Bs[128][40];
    const int tid = threadIdx.x;
    const int m0 = blockIdx.y * 128, n0 = blockIdx.x * 128;
    const int wave = tid >> 6, lane = tid & 63;
    const int wm = (wave & 1) * 64, wn = (wave >> 1) * 64;
    const int lm = lane & 15, quad = lane >> 4;
    f32x4 acc[4][4] = {};

    for (int k0 = 0; k0 < K; k0 += 32) {
#pragma unroll
        for (int r = 0; r < 2; ++r) {
            int seg = tid + r * 256;                  // 0..511
            int row = seg >> 2, c16 = (seg & 3) << 3; // 8 bf16 per 16B
            uint4 va = *(const uint4*)(A + (size_t)(m0 + row) * K + k0 + c16);
            *(uint4*)&As[row][c16] = va;
            uint4 vb = *(const uint4*)(B + (size_t)(n0 + row) * K + k0 + c16);
            *(uint4*)&Bs[row][c16] = vb;
        }
        __syncthreads();
        bf16x8 af[4], bfr[4];
#pragma unroll
        for (int i = 0; i < 4; ++i) {
            af[i]  = *(const bf16x8*)&As[wm + i * 16 + lm][quad * 8];
            bfr[i] = *(const bf16x8*)&Bs[wn + i * 16 + lm][quad * 8];
        }
#pragma unroll
        for (int mi = 0; mi < 4; ++mi)
#pragma unroll
            for (int ni = 0; ni < 4; ++ni)
                acc[mi][ni] = __builtin_amdgcn_mfma_f32_16x16x32_bf16(
                    af[mi], bfr[ni], acc[mi][ni], 0, 0, 0);
        __syncthreads();
    }

    const int rbase = quad * 4;
#pragma unroll
    for (int mi = 0; mi < 4; ++mi) {
#pragma unroll
        for (int ni = 0; ni < 4; ++ni) {
            const int col = n0 + wn + ni * 16 + lm;
            const float bv = (mode == 0) ? bias[col] : 0.0f;
#pragma unroll
            for (int r = 0; r < 4; ++r) {
                const int row = m0 + wm + mi * 16 + rbase + r;
                float v = acc[mi][ni][r];
                if (mode == 0)
                    ((unsigned short*)Cout)[(size_t)row * N + col] = f2bf(v + bv);
                else
                    ((float*)Cout)[(size_t)row * N + col] = sigm(v);
            }
        }
    }
}

// ---------------------------------------------------------------------------
// K3: LSTM scan v4 — single barrier per step, in-wave gate gather.
//     Thread map: unit = tid>>3, gate = (tid&7)>>1, p = tid&1 — the 8 lanes
//     of one unit are adjacent, so half-dot combine (shfl_xor 1) and i/f/g/o
//     gather (shfl +2/+4/+6) stay in-wave; no lpre LDS, no 2nd barrier.
//     LDS h double-buffered by step parity -> one __syncthreads per step.
//     launch_bounds(768,3): 12 waves/CU, VGPR cap ~170 so the 96 weight
//     dwords stay in arch VGPRs (round-9 kernel showed VGPR=68 < 96 ->
//     weights were in AGPRs/reloads).
//     Exchange: proven fence-free tag-u64 agent-scope scheme (lead <= 1).
// ---------------------------------------------------------------------------
#define WLOAD(i) const uint4 wr##i = wq[i];
#define WDOT(i) \
    a0 = dot2acc(__builtin_bit_cast(h2, wr##i.x), hp[4*(i)+0], a0); \
    a1 = dot2acc(__builtin_bit_cast(h2, wr##i.y), hp[4*(i)+1], a1); \
    a2 = dot2acc(__builtin_bit_cast(h2, wr##i.z), hp[4*(i)+2], a2); \
    a3 = dot2acc(__builtin_bit_cast(h2, wr##i.w), hp[4*(i)+3], a3);

__global__ __launch_bounds__(768, 3) void lstm_scan4(
    const unsigned* __restrict__ wpk,          // [2][1536][192] fp16-pairs
    const unsigned short* __restrict__ pre,    // [2][B][S][1536] bf16
    unsigned short* __restrict__ h_sb,         // [S][B][768] bf16
    unsigned long long* __restrict__ hx64) {   // [2][64][384] {tag,val}
    const int blk   = blockIdx.x;
    const int chain = blk & 63;                // dir*32 + b   (same-XCD swizzle)
    const int bp    = blk >> 6;
    const int d = chain >> 5, b = chain & 31;
    const int tid = threadIdx.x;
    const int lane = tid & 63;
    const int unit = tid >> 3;                 // [0,96)
    const int sub  = tid & 7;
    const int gate = sub >> 1;                 // i,f,g,o
    const int p    = sub & 1;                  // half of the 384-dot
    const int base = bp * 96;
    const int G = gate * 384 + base + unit;    // global gate row

    __shared__ __align__(16) _Float16 lh16[2][384];

    const uint4* wq = (const uint4*)(wpk + ((size_t)d * 1536 + G) * 192 + p * 96);
    WLOAD(0)  WLOAD(1)  WLOAD(2)  WLOAD(3)  WLOAD(4)  WLOAD(5)
    WLOAD(6)  WLOAD(7)  WLOAD(8)  WLOAD(9)  WLOAD(10) WLOAD(11)
    WLOAD(12) WLOAD(13) WLOAD(14) WLOAD(15) WLOAD(16) WLOAD(17)
    WLOAD(18) WLOAD(19) WLOAD(20) WLOAD(21) WLOAD(22) WLOAD(23)

    const unsigned short* prb = pre + ((size_t)d * B_SZ + b) * S_LEN * G4;
    float c = 0.0f;

    for (int s = 0; s < S_LEN; ++s) {
        const int t = d ? (S_LEN - 1 - s) : s;
        const int lb = s & 1;
        float prev = bf2f(prb[(size_t)t * G4 + G]);   // issue early

        // ---- stage h(s-1): remote 288 via tag-poll, own 96 written last iter
        if (s == 0) {
            if (tid < 384) lh16[0][tid] = (_Float16)0.0f;
        } else if (tid < 288) {
            const int uu = tid + (tid >= base ? 96 : 0);
            const unsigned long long* srcp =
                hx64 + ((size_t)((s - 1) & 1) * 64 + chain) * 384 + uu;
            unsigned long long v =
                __hip_atomic_load(srcp, __ATOMIC_RELAXED, __HIP_MEMORY_SCOPE_AGENT);
            while ((unsigned)(v >> 32) != (unsigned)(s - 1)) {
                __builtin_amdgcn_s_sleep(1);
                v = __hip_atomic_load(srcp, __ATOMIC_RELAXED, __HIP_MEMORY_SCOPE_AGENT);
            }
            lh16[lb][uu] = (_Float16)__builtin_bit_cast(float, (unsigned)v);
        }
        __syncthreads();                       // the ONLY barrier per step

        // ---- half-row dot against broadcast h
        float full;
        {
            const h2* hp = ((const h2*)lh16[lb]) + p * 96;
            float a0 = (p == 0) ? prev : 0.0f, a1 = 0.f, a2 = 0.f, a3 = 0.f;
            WDOT(0)  WDOT(1)  WDOT(2)  WDOT(3)  WDOT(4)  WDOT(5)
            WDOT(6)  WDOT(7)  WDOT(8)  WDOT(9)  WDOT(10) WDOT(11)
            WDOT(12) WDOT(13) WDOT(14) WDOT(15) WDOT(16) WDOT(17)
            WDOT(18) WDOT(19) WDOT(20) WDOT(21) WDOT(22) WDOT(23)
            float acc = (a0 + a1) + (a2 + a3);
            full = acc + __shfl_xor(acc, 1, 64);   // combine halves (in-wave)
        }

        // ---- gather i,f,g,o to sub==0 lanes (in-wave), update, publish
        float gf = __shfl(full, lane + 2, 64);
        float gg = __shfl(full, lane + 4, 64);
        float go = __shfl(full, lane + 6, 64);
        if (sub == 0) {
            c = sigm(gf) * c + sigm(full) * tanh_fast(gg);
            float h = sigm(go) * tanh_fast(c);
            h_sb[((size_t)t * B_SZ + b) * HID + d * DH + base + unit] = f2bf(h);
            lh16[lb ^ 1][base + unit] = (_Float16)h;    // own h for next step
            unsigned long long v = ((unsigned long long)(unsigned)s << 32)
                                 | (unsigned long long)__builtin_bit_cast(unsigned, h);
            __hip_atomic_store(hx64 + ((size_t)lb * 64 + chain) * 384 + base + unit,
                               v, __ATOMIC_RELAXED, __HIP_MEMORY_SCOPE_AGENT);
        }
    }
}

// ---------------------------------------------------------------------------
// K5: gated highway recurrence as a parallel chunked linear scan.
//     Reads bf16 h_s (h_sb), writes fp32 h_tilde into hs (gscanC).
// ---------------------------------------------------------------------------
__global__ __launch_bounds__(256) void gscanA(
    const float* __restrict__ g, const unsigned short* __restrict__ hsb,
    float2* __restrict__ ab) {                 // [NCHK][NCH]
    int id = blockIdx.x * 256 + threadIdx.x;   // < NCHK*NCH
    int chunk = id / NCH, chain = id - chunk * NCH;
    int t0 = chunk * CHK;
    float A = 1.f, Bv = 0.f;
    for (int i = 0; i < CHK; ++i) {
        int t = t0 + i;
        size_t idx = (size_t)t * NCH + chain;
        float gv = g[idx];
        float hv = bf2f(hsb[idx]);
        float a = (t == 0) ? 0.f : (1.f - gv);
        float bb = (t == 0) ? hv : gv * hv;
        A  = a * A;
        Bv = a * Bv + bb;
    }
    ab[id] = make_float2(A, Bv);
}

__global__ __launch_bounds__(256) void gscanB(
    const float2* __restrict__ ab, float* __restrict__ cin) {  // [NCHK][NCH]
    int chain = blockIdx.x * 256 + threadIdx.x;   // < NCH
    float h = 0.f;
#pragma unroll
    for (int j = 0; j < NCHK; ++j) {
        cin[(size_t)j * NCH + chain] = h;
        float2 t = ab[(size_t)j * NCH + chain];
        h = t.x * h + t.y;
    }
}

__global__ __launch_bounds__(256) void gscanC(
    const float* __restrict__ g, const unsigned short* __restrict__ hsb,
    float* __restrict__ hs, const float* __restrict__ cin) {
    int id = blockIdx.x * 256 + threadIdx.x;
    int chunk = id / NCH, chain = id - chunk * NCH;
    int t0 = chunk * CHK;
    float h = cin[(size_t)chunk * NCH + chain];
    for (int i = 0; i < CHK; ++i) {
        int t = t0 + i;
        size_t idx = (size_t)t * NCH + chain;
        float gv = g[idx];
        float v  = bf2f(hsb[idx]);
        h = (t == 0) ? v : (gv * v + (1.f - gv) * h);
        hs[idx] = h;
    }
}

// ---------------------------------------------------------------------------
// K6: upper head + mix + CE(labels). NO atomics: per-block partial sums.
// ---------------------------------------------------------------------------
__global__ __launch_bounds__(256) void final_k(
    const float* __restrict__ ht, const float* __restrict__ Wup,
    const float* __restrict__ bup, const float* __restrict__ alpha,
    const float* __restrict__ zsp, const int* __restrict__ labels,
    const int* __restrict__ amask, float* __restrict__ out, float* __restrict__ p1) {
    const int gid = blockIdx.x * blockDim.x + threadIdx.x;
    const int pos = gid >> 6, lane = gid & 63, wv = threadIdx.x >> 6;
    __shared__ float r1[4];
    const int bb = pos >> 9, tt = pos & 511;
    const float* hp = ht + (size_t)tt * (B_SZ * HID) + (size_t)bb * HID;
    float acc[7] = {};
#pragma unroll
    for (int j = 0; j < 12; ++j) {
        int k = lane + (j << 6);
        float hv = hp[k];
        const float* wr = Wup + k * 7;
#pragma unroll
        for (int cc = 0; cc < 7; ++cc) acc[cc] += hv * wr[cc];
    }
#pragma unroll
    for (int cc = 0; cc < 7; ++cc) acc[cc] = wred(acc[cc]);
    if (lane == 0) {
        float al = alpha[pos];
        float z[7], mx = -1e30f;
#pragma unroll
        for (int cc = 0; cc < 7; ++cc) {
            float v = acc[cc] + bup[cc];
            v = zsp[(size_t)pos * 7 + cc] * al + v * (1.0f - al);
            z[cc] = v;
            mx = fmaxf(mx, v);
            out[1 + (size_t)pos * 7 + cc] = v;
        }
        float se = 0.f;
#pragma unroll
        for (int cc = 0; cc < 7; ++cc) se += __expf(z[cc] - mx);
        float lse = mx + __logf(se);
        int lab = labels[pos];
        float zl = z[0];
#pragma unroll
        for (int cc = 1; cc < 7; ++cc) if (lab == cc) zl = z[cc];
        float m = (float)amask[pos];
        r1[wv] = (lse - zl) * m;
    }
    __syncthreads();
    if (threadIdx.x == 0)
        p1[blockIdx.x] = r1[0] + r1[1] + r1[2] + r1[3];
}

// ---------------------------------------------------------------------------
// K7: grid reduction of partials -> d_out[0]. One block, 256 threads.
// ---------------------------------------------------------------------------
__global__ __launch_bounds__(256) void loss_k(
    const float* __restrict__ p0, const float* __restrict__ p1,
    const float* __restrict__ p2, float* __restrict__ out) {
    const int tid = threadIdx.x, lane = tid & 63, wv = tid >> 6;
    __shared__ float rs[4][3];
    float s0 = 0.f, s1 = 0.f, s2 = 0.f;
    for (int i = tid; i < 4096; i += 256) {
        s0 += p0[i]; s1 += p1[i]; s2 += p2[i];
    }
    s0 = wred(s0); s1 = wred(s1); s2 = wred(s2);
    if (lane == 0) { rs[wv][0] = s0; rs[wv][1] = s1; rs[wv][2] = s2; }
    __syncthreads();
    if (tid == 0) {
        float t0 = rs[0][0] + rs[1][0] + rs[2][0] + rs[3][0];
        float t1 = rs[0][1] + rs[1][1] + rs[2][1] + rs[3][1];
        float t2 = rs[0][2] + rs[1][2] + rs[2][2] + rs[3][2];
        out[0] = t0 / t2 + t1 / t2;
    }
}

// ---------------------------------------------------------------------------
extern "C" void kernel_launch(void* const* d_in, const int* in_sizes, int n_in,
                              void* d_out, int out_size, void* d_ws, size_t ws_size,
                              hipStream_t stream) {
    const float* x     = (const float*)d_in[0];
    const int*   amask = (const int*)d_in[1];
    const int*   labels= (const int*)d_in[2];
    const int*   labn  = (const int*)d_in[3];
    const float* Wfc   = (const float*)d_in[4];
    const float* bfc   = (const float*)d_in[5];
    const float* wihf  = (const float*)d_in[6];
    const float* whhf  = (const float*)d_in[7];
    const float* bf    = (const float*)d_in[8];
    const float* wihb  = (const float*)d_in[9];
    const float* whhb  = (const float*)d_in[10];
    const float* bb    = (const float*)d_in[11];
    const float* Wg    = (const float*)d_in[12];
    const float* Wup   = (const float*)d_in[13];
    const float* bup   = (const float*)d_in[14];
    const float* Wtr   = (const float*)d_in[15];
    float* out = (float*)d_out;
    (void)in_sizes; (void)n_in; (void)out_size; (void)ws_size;

    char* ws = (char*)d_ws;
    size_t off = 0;
    auto alloc = [&](size_t bytes) -> char* {
        char* p = ws + off;
        off = (off + bytes + 255) & ~(size_t)255;
        return p;
    };
    unsigned* w16buf    = (unsigned*)alloc((size_t)2 * 1536 * 192 * 4);        // 2.36 MB
    unsigned short* pre = (unsigned short*)alloc((size_t)2 * NPOS * G4 * 2);   // 96 MB
    float* hs           = (float*)alloc((size_t)NPOS * HID * 4);               // 48 MB
    unsigned short* xb  = (unsigned short*)alloc((size_t)NPOS * HID * 2);      // 24 MB (reused as h_sb)
    unsigned short* wfb = (unsigned short*)alloc((size_t)G4 * HID * 2);        // 2.36 MB
    unsigned short* wbb = (unsigned short*)alloc((size_t)G4 * HID * 2);        // 2.36 MB
    unsigned short* wgt = (unsigned short*)alloc((size_t)HID * HID * 2);       // 1.18 MB
    float* alpha        = (float*)alloc((size_t)NPOS * 4);
    float* zsp          = (float*)alloc((size_t)NPOS * 7 * 4);
    unsigned long long* hx64 = (unsigned long long*)alloc((size_t)2 * 64 * 384 * 8); // 393 KB
    float2* ab          = (float2*)alloc((size_t)NCHK * NCH * 8);              // 1.57 MB
    float* cin          = (float*)alloc((size_t)NCHK * NCH * 4);               // 786 KB
    float* part0        = (float*)alloc(4096 * 4);
    float* part1        = (float*)alloc(4096 * 4);
    float* part2        = (float*)alloc(4096 * 4);
    float* gbuf          = (float*)pre;   // alias: pre dead after lstm_scan4
    unsigned short* h_sb = xb;            // alias: xb dead after pre-GEMMs

    // hx64 needs no init: 0xAA poison tag never matches a step tag in [0,512).

    wprep<<<2304, 256, 0, stream>>>(whhf, whhb, w16buf);
    cast_bf16<<<12288, 256, 0, stream>>>(x, xb, NPOS * HID / 4);
    cast_bf16<<<1152, 256, 0, stream>>>(wihf, wfb, G4 * HID / 4);
    cast_bf16<<<1152, 256, 0, stream>>>(wihb, wbb, G4 * HID / 4);
    wgt_prep<<<2304, 256, 0, stream>>>(Wg, wgt);

    zt_kernel<<<4096, 256, 0, stream>>>(x, amask, labn, Wfc, bfc, Wtr, alpha, zsp,
                                        part0, part2);

    // pre = x @ w_ih^T + b  (both directions), bf16 out
    gemm_mfma<<<dim3(12, 128), 256, 0, stream>>>(xb, wfb, bf, pre, NPOS, G4, HID, 0);
    gemm_mfma<<<dim3(12, 128), 256, 0, stream>>>(xb, wbb, bb, pre + (size_t)NPOS * G4,
                                                 NPOS, G4, HID, 0);

    lstm_scan4<<<256, 768, 0, stream>>>(w16buf, pre, h_sb, hx64);

    // g = sigmoid(h_s @ W_gate), fp32 out (gbuf aliases pre)
    gemm_mfma<<<dim3(6, 128), 256, 0, stream>>>(h_sb, wgt, nullptr, gbuf, NPOS, HID, HID, 1);

    // gated highway recurrence: parallel chunked linear scan (bf16 in, fp32 out)
    gscanA<<<768, 256, 0, stream>>>(gbuf, h_sb, ab);
    gscanB<<<96, 256, 0, stream>>>(ab, cin);
    gscanC<<<768, 256, 0, stream>>>(gbuf, h_sb, hs, cin);

    final_k<<<4096, 256, 0, stream>>>(hs, Wup, bup, alpha, zsp, labels, amask, out, part1);

    loss_k<<<1, 256, 0, stream>>>(part0, part1, part2, out);
}

// Round 11
// 1271.393 us; speedup vs baseline: 1.1576x; 1.1576x over previous
//
#include <hip/hip_runtime.h>

#define B_SZ   32
#define S_LEN  512
#define HID    768
#define DH     384
#define G4     1536
#define NPOS   16384   // B_SZ * S_LEN
#define EPS_C  0.5f
#define NCH    24576   // B_SZ * HID channels
#define CHK    64      // gate-scan chunk length
#define NCHK   8       // S_LEN / CHK

typedef _Float16 h2 __attribute__((ext_vector_type(2)));
typedef short bf16x8 __attribute__((ext_vector_type(8)));
typedef float f32x4 __attribute__((ext_vector_type(4)));

static __device__ __forceinline__ float sigm(float x) { return 1.0f / (1.0f + __expf(-x)); }
static __device__ __forceinline__ float tanh_fast(float x) {
    return 1.0f - 2.0f / (__expf(2.0f * x) + 1.0f);
}

static __device__ __forceinline__ unsigned short f2bf(float f) {
    union { float f; unsigned u; } v; v.f = f;
    unsigned r = v.u + 0x7FFF + ((v.u >> 16) & 1);
    return (unsigned short)(r >> 16);
}
static __device__ __forceinline__ float bf2f(unsigned short u) {
    union { unsigned u; float f; } v; v.u = ((unsigned)u) << 16; return v.f;
}

static __device__ __forceinline__ float wred(float v) {
#pragma unroll
    for (int off = 32; off > 0; off >>= 1) v += __shfl_down(v, off, 64);
    return v;
}

static __device__ __forceinline__ float dot2acc(h2 a, h2 b, float c) {
#if __has_builtin(__builtin_amdgcn_fdot2)
    return __builtin_amdgcn_fdot2(a, b, c, false);
#else
    return c + (float)a.x * (float)b.x + (float)a.y * (float)b.y;
#endif
}

// ---------------------------------------------------------------------------
// K0a: pack w_hh fp32 [1536,384] -> fp16-pair u32 [2][1536][192]  (scan wts)
// ---------------------------------------------------------------------------
__global__ void wprep(const float* __restrict__ wf, const float* __restrict__ wb,
                      unsigned* __restrict__ wpk) {
    int gid = blockIdx.x * 256 + threadIdx.x;       // < 589824
    int d = (gid >= 294912) ? 1 : 0;
    int j = gid - d * 294912;
    const float* src = d ? wb : wf;
    _Float16 a = (_Float16)src[2 * j];
    _Float16 b = (_Float16)src[2 * j + 1];
    unsigned pa = __builtin_bit_cast(unsigned short, a);
    unsigned pb = __builtin_bit_cast(unsigned short, b);
    wpk[(size_t)d * 294912 + j] = pa | (pb << 16);
}

// ---------------------------------------------------------------------------
// K0b: fp32 -> bf16 cast (n multiple of 4)
// ---------------------------------------------------------------------------
__global__ __launch_bounds__(256) void cast_bf16(
    const float* __restrict__ src, unsigned short* __restrict__ dst, int n4) {
    int i = blockIdx.x * 256 + threadIdx.x;
    if (i >= n4) return;
    float4 v = *(const float4*)(src + (size_t)i * 4);
    ushort4 o;
    o.x = f2bf(v.x); o.y = f2bf(v.y); o.z = f2bf(v.z); o.w = f2bf(v.w);
    *(ushort4*)(dst + (size_t)i * 4) = o;
}

// ---------------------------------------------------------------------------
// K0c: W_gate [K=768][N=768] -> bf16 transposed [N][K] (read-coalesced)
// ---------------------------------------------------------------------------
__global__ __launch_bounds__(256) void wgt_prep(
    const float* __restrict__ Wg, unsigned short* __restrict__ Wgt) {
    int i = blockIdx.x * 256 + threadIdx.x;          // < 589824
    int k = i / 768, n = i - k * 768;
    Wgt[(size_t)n * 768 + k] = f2bf(Wg[i]);
}

// ---------------------------------------------------------------------------
// K1: z_t head. One wave / position. NO atomics: per-block partial sums.
// ---------------------------------------------------------------------------
__global__ __launch_bounds__(256) void zt_kernel(
    const float* __restrict__ x, const int* __restrict__ amask,
    const int* __restrict__ labn, const float* __restrict__ Wfc,
    const float* __restrict__ bfc, const float* __restrict__ Wtr,
    float* __restrict__ alpha, float* __restrict__ zsp,
    float* __restrict__ p0, float* __restrict__ p2) {
    const int gid  = blockIdx.x * blockDim.x + threadIdx.x;
    const int pos  = gid >> 6, lane = gid & 63, wv = threadIdx.x >> 6;
    __shared__ float r0[4], r2[4];
    const float* xp = x + (size_t)pos * HID;
    float a0 = 0.f, a1 = 0.f, a2 = 0.f;
#pragma unroll
    for (int j = 0; j < 12; ++j) {
        int k = lane + (j << 6);
        float xv = xp[k];
        a0 += xv * Wfc[k * 3 + 0];
        a1 += xv * Wfc[k * 3 + 1];
        a2 += xv * Wfc[k * 3 + 2];
    }
    a0 = wred(a0); a1 = wred(a1); a2 = wred(a2);
    if (lane == 0) {
        float z0 = a0 + bfc[0], z1 = a1 + bfc[1], z2 = a2 + bfc[2];
        float mx = fmaxf(z0, fmaxf(z1, z2));
        float e0 = __expf(z0 - mx), e1 = __expf(z1 - mx), e2 = __expf(z2 - mx);
        float se = e0 + e1 + e2;
        float m  = (float)amask[pos];
        int  lab = labn[pos];
        float zl = (lab == 0) ? z0 : ((lab == 1) ? z1 : z2);
        r0[wv] = (mx + __logf(se) - zl) * m;
        r2[wv] = m;
        float q0 = e0 / se, q1 = e1 / se, q2 = e2 / se;
        alpha[pos] = EPS_C * (q0 * q0 + q1 * q1 + q2 * q2);
#pragma unroll
        for (int cc = 0; cc < 7; ++cc)
            zsp[(size_t)pos * 7 + cc] = z0 * Wtr[cc] + z1 * Wtr[7 + cc] + z2 * Wtr[14 + cc];
    }
    __syncthreads();
    if (threadIdx.x == 0) {
        p0[blockIdx.x] = r0[0] + r0[1] + r0[2] + r0[3];
        p2[blockIdx.x] = r2[0] + r2[1] + r2[2] + r2[3];
    }
}

// ---------------------------------------------------------------------------
// K2: bf16 MFMA GEMM.  C[M,N] = A[M,K] * B[N,K]^T.
//     mode 0: +bias, bf16 out.   mode 1: sigmoid, bf16 out (no bias).
// ---------------------------------------------------------------------------
__global__ __launch_bounds__(256) void gemm_mfma(
    const unsigned short* __restrict__ A, const unsigned short* __restrict__ B,
    const float* __restrict__ bias, void* __restrict__ Cout,
    int M, int N, int K, int mode) {
    __shared__ __align__(16) unsigned short As[128][40];   // +8 pad: conflict-free
    __shared__ __align__(16) unsigned short Bs[128][40];
    const int tid = threadIdx.x;
    const int m0 = blockIdx.y * 128, n0 = blockIdx.x * 128;
    const int wave = tid >> 6, lane = tid & 63;
    const int wm = (wave & 1) * 64, wn = (wave >> 1) * 64;
    const int lm = lane & 15, quad = lane >> 4;
    f32x4 acc[4][4] = {};

    for (int k0 = 0; k0 < K; k0 += 32) {
#pragma unroll
        for (int r = 0; r < 2; ++r) {
            int seg = tid + r * 256;                  // 0..511
            int row = seg >> 2, c16 = (seg & 3) << 3; // 8 bf16 per 16B
            uint4 va = *(const uint4*)(A + (size_t)(m0 + row) * K + k0 + c16);
            *(uint4*)&As[row][c16] = va;
            uint4 vb = *(const uint4*)(B + (size_t)(n0 + row) * K + k0 + c16);
            *(uint4*)&Bs[row][c16] = vb;
        }
        __syncthreads();
        bf16x8 af[4], bfr[4];
#pragma unroll
        for (int i = 0; i < 4; ++i) {
            af[i]  = *(const bf16x8*)&As[wm + i * 16 + lm][quad * 8];
            bfr[i] = *(const bf16x8*)&Bs[wn + i * 16 + lm][quad * 8];
        }
#pragma unroll
        for (int mi = 0; mi < 4; ++mi)
#pragma unroll
            for (int ni = 0; ni < 4; ++ni)
                acc[mi][ni] = __builtin_amdgcn_mfma_f32_16x16x32_bf16(
                    af[mi], bfr[ni], acc[mi][ni], 0, 0, 0);
        __syncthreads();
    }

    const int rbase = quad * 4;
#pragma unroll
    for (int mi = 0; mi < 4; ++mi) {
#pragma unroll
        for (int ni = 0; ni < 4; ++ni) {
            const int col = n0 + wn + ni * 16 + lm;
            const float bv = (mode == 0) ? bias[col] : 0.0f;
#pragma unroll
            for (int r = 0; r < 4; ++r) {
                const int row = m0 + wm + mi * 16 + rbase + r;
                float v = acc[mi][ni][r];
                if (mode == 0)
                    ((unsigned short*)Cout)[(size_t)row * N + col] = f2bf(v + bv);
                else
                    ((unsigned short*)Cout)[(size_t)row * N + col] = f2bf(sigm(v));
            }
        }
    }
}

// ---------------------------------------------------------------------------
// K3: LSTM scan v5 — v3 row-map + concentrated update (1.5 waves), but
//     barrier #2 replaced by per-row LDS tag handshakes (workgroup-scope
//     release/acquire = ds ops + lgkmcnt only; no L2 traffic):
//       writer (p==0): lpreV[r]=full; release-store lpreT[r]=s
//       update thread (tid<96): acquire-poll its 4 row tags, read lpreV.
//     lh16 double-buffered by parity (needed once barrier-2 is gone).
//     Publish moved FIRST in the update (inter-block critical path).
//     Cross-block exchange: proven fence-free tag-u64 scheme (lead <= 1).
// ---------------------------------------------------------------------------
#define WLOAD(i) const uint4 wr##i = wq[i];
#define WDOT(i) \
    a0 = dot2acc(__builtin_bit_cast(h2, wr##i.x), hp[4*(i)+0], a0); \
    a1 = dot2acc(__builtin_bit_cast(h2, wr##i.y), hp[4*(i)+1], a1); \
    a2 = dot2acc(__builtin_bit_cast(h2, wr##i.z), hp[4*(i)+2], a2); \
    a3 = dot2acc(__builtin_bit_cast(h2, wr##i.w), hp[4*(i)+3], a3);

__global__ __launch_bounds__(768) void lstm_scan5(
    const unsigned* __restrict__ wpk,          // [2][1536][192] fp16-pairs
    const unsigned short* __restrict__ pre,    // [2][B][S][1536] bf16
    unsigned short* __restrict__ h_sb,         // [S][B][768] bf16
    unsigned long long* __restrict__ hx64) {   // [2][64][384] {tag,val}
    const int blk   = blockIdx.x;
    const int chain = blk & 63;                // dir*32 + b   (same-XCD swizzle)
    const int bp    = blk >> 6;
    const int d = chain >> 5, b = chain & 31;
    const int tid = threadIdx.x;
    const int r = tid >> 1, p = tid & 1;
    const int g = r / 96;
    const int u = r - g * 96;
    const int base = bp * 96;
    const int G = g * 384 + base + u;          // global gate row (i,f,g,o)

    __shared__ __align__(16) _Float16 lh16[2][384];
    __shared__ float    lpreV[384];
    __shared__ unsigned lpreT[384];

    const uint4* wq = (const uint4*)(wpk + ((size_t)d * 1536 + G) * 192 + p * 96);
    WLOAD(0)  WLOAD(1)  WLOAD(2)  WLOAD(3)  WLOAD(4)  WLOAD(5)
    WLOAD(6)  WLOAD(7)  WLOAD(8)  WLOAD(9)  WLOAD(10) WLOAD(11)
    WLOAD(12) WLOAD(13) WLOAD(14) WLOAD(15) WLOAD(16) WLOAD(17)
    WLOAD(18) WLOAD(19) WLOAD(20) WLOAD(21) WLOAD(22) WLOAD(23)

    const unsigned short* prb = pre + ((size_t)d * B_SZ + b) * S_LEN * G4;
    float c = 0.0f;

    for (int s = 0; s < S_LEN; ++s) {
        const int t = d ? (S_LEN - 1 - s) : s;
        const int lb = s & 1;
        float prev = bf2f(prb[(size_t)t * G4 + G]);   // issue early

        // ---- stage h(s-1) into lh16[lb]: remote 288 via tag-poll
        if (s == 0) {
            if (tid < 384) { lh16[0][tid] = (_Float16)0.0f; lpreT[tid] = 0xFFFFFFFFu; }
        } else if (tid < 288) {
            const int uu = tid + (tid >= base ? 96 : 0);
            const unsigned long long* srcp =
                hx64 + ((size_t)((s - 1) & 1) * 64 + chain) * 384 + uu;
            unsigned long long v =
                __hip_atomic_load(srcp, __ATOMIC_RELAXED, __HIP_MEMORY_SCOPE_AGENT);
            while ((unsigned)(v >> 32) != (unsigned)(s - 1)) {
                __builtin_amdgcn_s_sleep(1);
                v = __hip_atomic_load(srcp, __ATOMIC_RELAXED, __HIP_MEMORY_SCOPE_AGENT);
            }
            lh16[lb][uu] = (_Float16)__builtin_bit_cast(float, (unsigned)v);
        }
        __syncthreads();                       // the only block-wide barrier

        // ---- half-row dot against broadcast h; row handshake via LDS tags
        {
            const h2* hp = ((const h2*)lh16[lb]) + p * 96;
            float a0 = (p == 0) ? prev : 0.0f, a1 = 0.f, a2 = 0.f, a3 = 0.f;
            WDOT(0)  WDOT(1)  WDOT(2)  WDOT(3)  WDOT(4)  WDOT(5)
            WDOT(6)  WDOT(7)  WDOT(8)  WDOT(9)  WDOT(10) WDOT(11)
            WDOT(12) WDOT(13) WDOT(14) WDOT(15) WDOT(16) WDOT(17)
            WDOT(18) WDOT(19) WDOT(20) WDOT(21) WDOT(22) WDOT(23)
            float acc = (a0 + a1) + (a2 + a3);
            float full = acc + __shfl_xor(acc, 1, 64);
            if (p == 0) {
                lpreV[r] = full;
                __hip_atomic_store(&lpreT[r], (unsigned)s, __ATOMIC_RELEASE,
                                   __HIP_MEMORY_SCOPE_WORKGROUP);
            }
        }

        // ---- state update (96 owner threads): poll 4 row tags, then update
        if (tid < 96) {
            const unsigned sv = (unsigned)s;
#pragma unroll
            for (int j = 0; j < 4; ++j) {
                unsigned* tp = &lpreT[j * 96 + tid];
                while (__hip_atomic_load(tp, __ATOMIC_ACQUIRE,
                                         __HIP_MEMORY_SCOPE_WORKGROUP) != sv) {}
            }
            float gi = lpreV[tid], gf = lpreV[96 + tid];
            float gg = lpreV[192 + tid], go = lpreV[288 + tid];
            c = sigm(gf) * c + sigm(gi) * tanh_fast(gg);
            float h = sigm(go) * tanh_fast(c);
            // publish FIRST: inter-block critical path
            unsigned long long v = ((unsigned long long)sv << 32)
                                 | (unsigned long long)__builtin_bit_cast(unsigned, h);
            __hip_atomic_store(hx64 + ((size_t)lb * 64 + chain) * 384 + base + tid,
                               v, __ATOMIC_RELAXED, __HIP_MEMORY_SCOPE_AGENT);
            h_sb[((size_t)t * B_SZ + b) * HID + d * DH + base + tid] = f2bf(h);
            lh16[lb ^ 1][base + tid] = (_Float16)h;    // own h for next step
        }
    }
}

// ---------------------------------------------------------------------------
// K5: gated highway recurrence as a parallel chunked linear scan.
//     g bf16, h_s bf16; gscanC runs IN-PLACE on h_sb (bf16 h_tilde out).
// ---------------------------------------------------------------------------
__global__ __launch_bounds__(256) void gscanA(
    const unsigned short* __restrict__ g, const unsigned short* __restrict__ hsb,
    float2* __restrict__ ab) {                 // [NCHK][NCH]
    int id = blockIdx.x * 256 + threadIdx.x;   // < NCHK*NCH
    int chunk = id / NCH, chain = id - chunk * NCH;
    int t0 = chunk * CHK;
    float A = 1.f, Bv = 0.f;
    for (int i = 0; i < CHK; ++i) {
        int t = t0 + i;
        size_t idx = (size_t)t * NCH + chain;
        float gv = bf2f(g[idx]);
        float hv = bf2f(hsb[idx]);
        float a = (t == 0) ? 0.f : (1.f - gv);
        float bb = (t == 0) ? hv : gv * hv;
        A  = a * A;
        Bv = a * Bv + bb;
    }
    ab[id] = make_float2(A, Bv);
}

__global__ __launch_bounds__(256) void gscanB(
    const float2* __restrict__ ab, float* __restrict__ cin) {  // [NCHK][NCH]
    int chain = blockIdx.x * 256 + threadIdx.x;   // < NCH
    float h = 0.f;
#pragma unroll
    for (int j = 0; j < NCHK; ++j) {
        cin[(size_t)j * NCH + chain] = h;
        float2 t = ab[(size_t)j * NCH + chain];
        h = t.x * h + t.y;
    }
}

__global__ __launch_bounds__(256) void gscanC(
    const unsigned short* __restrict__ g, unsigned short* __restrict__ hsb,
    const float* __restrict__ cin) {
    int id = blockIdx.x * 256 + threadIdx.x;
    int chunk = id / NCH, chain = id - chunk * NCH;
    int t0 = chunk * CHK;
    float h = cin[(size_t)chunk * NCH + chain];
    for (int i = 0; i < CHK; ++i) {
        int t = t0 + i;
        size_t idx = (size_t)t * NCH + chain;
        float gv = bf2f(g[idx]);
        float v  = bf2f(hsb[idx]);
        h = (t == 0) ? v : (gv * v + (1.f - gv) * h);
        hsb[idx] = f2bf(h);                    // in-place: h_tilde bf16
    }
}

// ---------------------------------------------------------------------------
// K6: upper head + mix + CE(labels). bf16 h_tilde input. No atomics.
// ---------------------------------------------------------------------------
__global__ __launch_bounds__(256) void final_k(
    const unsigned short* __restrict__ ht, const float* __restrict__ Wup,
    const float* __restrict__ bup, const float* __restrict__ alpha,
    const float* __restrict__ zsp, const int* __restrict__ labels,
    const int* __restrict__ amask, float* __restrict__ out, float* __restrict__ p1) {
    const int gid = blockIdx.x * blockDim.x + threadIdx.x;
    const int pos = gid >> 6, lane = gid & 63, wv = threadIdx.x >> 6;
    __shared__ float r1[4];
    const int bb = pos >> 9, tt = pos & 511;
    const unsigned short* hp = ht + (size_t)tt * (B_SZ * HID) + (size_t)bb * HID;
    float acc[7] = {};
#pragma unroll
    for (int j = 0; j < 12; ++j) {
        int k = lane + (j << 6);
        float hv = bf2f(hp[k]);
        const float* wr = Wup + k * 7;
#pragma unroll
        for (int cc = 0; cc < 7; ++cc) acc[cc] += hv * wr[cc];
    }
#pragma unroll
    for (int cc = 0; cc < 7; ++cc) acc[cc] = wred(acc[cc]);
    if (lane == 0) {
        float al = alpha[pos];
        float z[7], mx = -1e30f;
#pragma unroll
        for (int cc = 0; cc < 7; ++cc) {
            float v = acc[cc] + bup[cc];
            v = zsp[(size_t)pos * 7 + cc] * al + v * (1.0f - al);
            z[cc] = v;
            mx = fmaxf(mx, v);
            out[1 + (size_t)pos * 7 + cc] = v;
        }
        float se = 0.f;
#pragma unroll
        for (int cc = 0; cc < 7; ++cc) se += __expf(z[cc] - mx);
        float lse = mx + __logf(se);
        int lab = labels[pos];
        float zl = z[0];
#pragma unroll
        for (int cc = 1; cc < 7; ++cc) if (lab == cc) zl = z[cc];
        float m = (float)amask[pos];
        r1[wv] = (lse - zl) * m;
    }
    __syncthreads();
    if (threadIdx.x == 0)
        p1[blockIdx.x] = r1[0] + r1[1] + r1[2] + r1[3];
}

// ---------------------------------------------------------------------------
// K7: grid reduction of partials -> d_out[0]. One block, 256 threads.
// ---------------------------------------------------------------------------
__global__ __launch_bounds__(256) void loss_k(
    const float* __restrict__ p0, const float* __restrict__ p1,
    const float* __restrict__ p2, float* __restrict__ out) {
    const int tid = threadIdx.x, lane = tid & 63, wv = tid >> 6;
    __shared__ float rs[4][3];
    float s0 = 0.f, s1 = 0.f, s2 = 0.f;
    for (int i = tid; i < 4096; i += 256) {
        s0 += p0[i]; s1 += p1[i]; s2 += p2[i];
    }
    s0 = wred(s0); s1 = wred(s1); s2 = wred(s2);
    if (lane == 0) { rs[wv][0] = s0; rs[wv][1] = s1; rs[wv][2] = s2; }
    __syncthreads();
    if (tid == 0) {
        float t0 = rs[0][0] + rs[1][0] + rs[2][0] + rs[3][0];
        float t1 = rs[0][1] + rs[1][1] + rs[2][1] + rs[3][1];
        float t2 = rs[0][2] + rs[1][2] + rs[2][2] + rs[3][2];
        out[0] = t0 / t2 + t1 / t2;
    }
}

// ---------------------------------------------------------------------------
extern "C" void kernel_launch(void* const* d_in, const int* in_sizes, int n_in,
                              void* d_out, int out_size, void* d_ws, size_t ws_size,
                              hipStream_t stream) {
    const float* x     = (const float*)d_in[0];
    const int*   amask = (const int*)d_in[1];
    const int*   labels= (const int*)d_in[2];
    const int*   labn  = (const int*)d_in[3];
    const float* Wfc   = (const float*)d_in[4];
    const float* bfc   = (const float*)d_in[5];
    const float* wihf  = (const float*)d_in[6];
    const float* whhf  = (const float*)d_in[7];
    const float* bf    = (const float*)d_in[8];
    const float* wihb  = (const float*)d_in[9];
    const float* whhb  = (const float*)d_in[10];
    const float* bb    = (const float*)d_in[11];
    const float* Wg    = (const float*)d_in[12];
    const float* Wup   = (const float*)d_in[13];
    const float* bup   = (const float*)d_in[14];
    const float* Wtr   = (const float*)d_in[15];
    float* out = (float*)d_out;
    (void)in_sizes; (void)n_in; (void)out_size; (void)ws_size;

    char* ws = (char*)d_ws;
    size_t off = 0;
    auto alloc = [&](size_t bytes) -> char* {
        char* p = ws + off;
        off = (off + bytes + 255) & ~(size_t)255;
        return p;
    };
    unsigned* w16buf    = (unsigned*)alloc((size_t)2 * 1536 * 192 * 4);        // 2.36 MB
    unsigned short* pre = (unsigned short*)alloc((size_t)2 * NPOS * G4 * 2);   // 96 MB
    unsigned short* xb  = (unsigned short*)alloc((size_t)NPOS * HID * 2);      // 24 MB (reused as h_sb)
    unsigned short* wfb = (unsigned short*)alloc((size_t)G4 * HID * 2);        // 2.36 MB
    unsigned short* wbb = (unsigned short*)alloc((size_t)G4 * HID * 2);        // 2.36 MB
    unsigned short* wgt = (unsigned short*)alloc((size_t)HID * HID * 2);       // 1.18 MB
    float* alpha        = (float*)alloc((size_t)NPOS * 4);
    float* zsp          = (float*)alloc((size_t)NPOS * 7 * 4);
    unsigned long long* hx64 = (unsigned long long*)alloc((size_t)2 * 64 * 384 * 8); // 393 KB
    float2* ab          = (float2*)alloc((size_t)NCHK * NCH * 8);              // 1.57 MB
    float* cin          = (float*)alloc((size_t)NCHK * NCH * 4);               // 786 KB
    float* part0        = (float*)alloc(4096 * 4);
    float* part1        = (float*)alloc(4096 * 4);
    float* part2        = (float*)alloc(4096 * 4);
    unsigned short* gbuf = (unsigned short*)pre;  // alias: pre dead after lstm_scan5
    unsigned short* h_sb = xb;                    // alias: xb dead after pre-GEMMs

    // hx64 needs no init: 0xAA poison tag never matches a step tag in [0,512).

    wprep<<<2304, 256, 0, stream>>>(whhf, whhb, w16buf);
    cast_bf16<<<12288, 256, 0, stream>>>(x, xb, NPOS * HID / 4);
    cast_bf16<<<1152, 256, 0, stream>>>(wihf, wfb, G4 * HID / 4);
    cast_bf16<<<1152, 256, 0, stream>>>(wihb, wbb, G4 * HID / 4);
    wgt_prep<<<2304, 256, 0, stream>>>(Wg, wgt);

    zt_kernel<<<4096, 256, 0, stream>>>(x, amask, labn, Wfc, bfc, Wtr, alpha, zsp,
                                        part0, part2);

    // pre = x @ w_ih^T + b  (both directions), bf16 out
    gemm_mfma<<<dim3(12, 128), 256, 0, stream>>>(xb, wfb, bf, pre, NPOS, G4, HID, 0);
    gemm_mfma<<<dim3(12, 128), 256, 0, stream>>>(xb, wbb, bb, pre + (size_t)NPOS * G4,
                                                 NPOS, G4, HID, 0);

    lstm_scan5<<<256, 768, 0, stream>>>(w16buf, pre, h_sb, hx64);

    // g = sigmoid(h_s @ W_gate), bf16 out (gbuf aliases pre)
    gemm_mfma<<<dim3(6, 128), 256, 0, stream>>>(h_sb, wgt, nullptr, gbuf, NPOS, HID, HID, 1);

    // gated highway recurrence: parallel chunked linear scan (bf16, in-place)
    gscanA<<<768, 256, 0, stream>>>(gbuf, h_sb, ab);
    gscanB<<<96, 256, 0, stream>>>(ab, cin);
    gscanC<<<768, 256, 0, stream>>>(gbuf, h_sb, cin);

    final_k<<<4096, 256, 0, stream>>>(h_sb, Wup, bup, alpha, zsp, labels, amask, out, part1);

    loss_k<<<1, 256, 0, stream>>>(part0, part1, part2, out);
}